// Round 1
// baseline (137.520 us; speedup 1.0000x reference)
//
#include <hip/hip_runtime.h>
#include <hip/hip_bf16.h>
#include <stdint.h>

typedef __bf16 bf16_t;
typedef __bf16 bf16x8 __attribute__((ext_vector_type(8)));
typedef __bf16 bf16x4v __attribute__((ext_vector_type(4)));
typedef float  f32x4  __attribute__((ext_vector_type(4)));

#define NEG_BIG (-1e10f)

// async global->LDS, 16B per lane; LDS dest = wave-uniform base + lane*16
__device__ __forceinline__ void load_lds16(const void* gsrc, void* ldst) {
  __builtin_amdgcn_global_load_lds(
      (__attribute__((address_space(1))) void*)(gsrc),
      (__attribute__((address_space(3))) void*)(ldst), 16, 0, 0);
}

// ---------------- 1) fused add + bf16 cast ----------------
__global__ __launch_bounds__(256) void k_prep(
    const float4* __restrict__ iq, const float4* __restrict__ ikv,
    const float4* __restrict__ pq, const float4* __restrict__ pk,
    const float4* __restrict__ pv,
    bf16_t* __restrict__ Xq, bf16_t* __restrict__ Xk, bf16_t* __restrict__ Xv)
{
  int i = blockIdx.x * 256 + threadIdx.x;   // 0 .. 4096*1024/4
  float4 a = iq[i], b = ikv[i];
  float4 eq = pq[i], ek = pk[i], ev = pv[i];
  bf16x4v q, k, v;
  q[0] = (bf16_t)(a.x + eq.x); q[1] = (bf16_t)(a.y + eq.y);
  q[2] = (bf16_t)(a.z + eq.z); q[3] = (bf16_t)(a.w + eq.w);
  k[0] = (bf16_t)(b.x + ek.x); k[1] = (bf16_t)(b.y + ek.y);
  k[2] = (bf16_t)(b.z + ek.z); k[3] = (bf16_t)(b.w + ek.w);
  v[0] = (bf16_t)(b.x + ev.x); v[1] = (bf16_t)(b.y + ev.y);
  v[2] = (bf16_t)(b.z + ev.z); v[3] = (bf16_t)(b.w + ev.w);
  *(bf16x4v*)&Xq[(size_t)i*4] = q;
  *(bf16x4v*)&Xk[(size_t)i*4] = k;
  *(bf16x4v*)&Xv[(size_t)i*4] = v;
}

// ---------------- 2) weight transpose + cast: W[k][n] -> Wt[n][k] bf16 ----------------
__global__ __launch_bounds__(256) void k_wtrans(
    const float* __restrict__ wq, const float* __restrict__ wk,
    const float* __restrict__ wv, const float* __restrict__ wo,
    bf16_t* __restrict__ Wqt, bf16_t* __restrict__ Wkt,
    bf16_t* __restrict__ Wvt, bf16_t* __restrict__ Wot)
{
  __shared__ float t[64][65];
  int z = blockIdx.z;
  const float* src = z==0 ? wq : z==1 ? wk : z==2 ? wv : wo;
  bf16_t*      dst = z==0 ? Wqt : z==1 ? Wkt : z==2 ? Wvt : Wot;
  int n0 = blockIdx.x * 64, k0 = blockIdx.y * 64;
  int c = threadIdx.x & 63, rb = threadIdx.x >> 6;
  #pragma unroll
  for (int i = 0; i < 16; ++i) {
    int r = i*4 + rb;
    t[r][c] = src[(size_t)(k0 + r)*1024 + n0 + c];
  }
  __syncthreads();
  #pragma unroll
  for (int i = 0; i < 16; ++i) {
    int r = i*4 + rb;
    dst[(size_t)(n0 + r)*1024 + k0 + c] = (bf16_t)t[c][r];
  }
}

// ---------------- 3) QKV GEMM: C = A(M x 1024) * Bt(N x 1024)^T, 128x128 tile, BK=64 ----------------
__global__ __launch_bounds__(256, 2) void k_gemm_qkv(
    const bf16_t* __restrict__ Xq, const bf16_t* __restrict__ Xk, const bf16_t* __restrict__ Xv,
    const bf16_t* __restrict__ Wqt, const bf16_t* __restrict__ Wkt, const bf16_t* __restrict__ Wvt,
    const float* __restrict__ bq, const float* __restrict__ bk, const float* __restrict__ bv,
    bf16_t* __restrict__ Qo, bf16_t* __restrict__ Ko, bf16_t* __restrict__ Vo)
{
  int z = blockIdx.z;
  const bf16_t* A  = z==0 ? Xq : z==1 ? Xk : Xv;
  const bf16_t* Bt = z==0 ? Wqt : z==1 ? Wkt : Wvt;
  const float* bias = z==0 ? bq : z==1 ? bk : bv;
  bf16_t* C = z==0 ? Qo : z==1 ? Ko : Vo;
  const float scale = (z==0) ? 0.125f : 1.0f;

  __shared__ bf16_t As[128*64];
  __shared__ bf16_t Bs[128*64];

  const int tid = threadIdx.x, lane = tid & 63, wid = tid >> 6;
  const int wm = wid >> 1, wn = wid & 1;
  const int bm0 = blockIdx.y * 128, bn0 = blockIdx.x * 128;
  const int g = lane >> 4, c = lane & 15;

  f32x4 acc[4][4] = {};

  const int srow = wid*32 + (lane >> 3);  // + i*8
  const int sch  = lane & 7;

  for (int kt = 0; kt < 16; ++kt) {
    int k0 = kt * 64;
    #pragma unroll
    for (int i = 0; i < 4; ++i) {
      int r  = srow + i*8;
      int ca = sch ^ (r & 7);             // source pre-swizzle (chunk XOR row&7)
      load_lds16(A  + (size_t)(bm0 + r)*1024 + k0 + ca*8, &As[(wid*32 + i*8)*64]);
      load_lds16(Bt + (size_t)(bn0 + r)*1024 + k0 + ca*8, &Bs[(wid*32 + i*8)*64]);
    }
    __syncthreads();
    #pragma unroll
    for (int kk = 0; kk < 2; ++kk) {
      bf16x8 af[4], bfr[4];
      #pragma unroll
      for (int m = 0; m < 4; ++m) {
        int row = wm*64 + m*16 + c;
        int ch  = (kk*4 + g) ^ (row & 7);
        af[m] = *(const bf16x8*)&As[row*64 + ch*8];
      }
      #pragma unroll
      for (int n = 0; n < 4; ++n) {
        int row = wn*64 + n*16 + c;
        int ch  = (kk*4 + g) ^ (row & 7);
        bfr[n] = *(const bf16x8*)&Bs[row*64 + ch*8];
      }
      #pragma unroll
      for (int m = 0; m < 4; ++m)
        #pragma unroll
        for (int n = 0; n < 4; ++n)
          acc[m][n] = __builtin_amdgcn_mfma_f32_16x16x32_bf16(af[m], bfr[n], acc[m][n], 0, 0, 0);
    }
    __syncthreads();
  }

  #pragma unroll
  for (int n = 0; n < 4; ++n) {
    int col = bn0 + wn*64 + n*16 + c;
    float bn_ = bias[col];
    #pragma unroll
    for (int m = 0; m < 4; ++m) {
      int row0 = bm0 + wm*64 + m*16 + g*4;
      #pragma unroll
      for (int r = 0; r < 4; ++r) {
        float v = (acc[m][n][r] + bn_) * scale;
        C[(size_t)(row0 + r)*1024 + col] = (bf16_t)v;
      }
    }
  }
}

// ---------------- 4) V transpose: per (b,h) [s][hd] -> Vt[hd][s] ----------------
__global__ __launch_bounds__(256) void k_vtrans(
    const bf16_t* __restrict__ V, bf16_t* __restrict__ Vt)
{
  __shared__ uint32_t t[64][65];
  int bh = blockIdx.y;              // b*16+h
  int s0 = blockIdx.x * 64;
  int b = bh >> 4, h = bh & 15;
  int c = threadIdx.x & 63, rb = threadIdx.x >> 6;
  const uint16_t* src = (const uint16_t*)V + (size_t)(b*1024 + s0)*1024 + h*64;
  #pragma unroll
  for (int i = 0; i < 16; ++i) {
    int r = i*4 + rb;              // s within tile
    t[r][c] = src[(size_t)r*1024 + c];
  }
  __syncthreads();
  uint16_t* dst = (uint16_t*)Vt + (size_t)(bh*64)*1024 + s0;
  #pragma unroll
  for (int i = 0; i < 16; ++i) {
    int r = i*4 + rb;              // hd
    dst[(size_t)r*1024 + c] = (uint16_t)t[c][r];
  }
}

// ---------------- 5) flash attention: per (b,h,q-tile 128), 4 waves ----------------
__global__ __launch_bounds__(256, 2) void k_attn(
    const bf16_t* __restrict__ Qm, const bf16_t* __restrict__ Km,
    const bf16_t* __restrict__ Vt, const float* __restrict__ mask,
    bf16_t* __restrict__ X2)
{
  __shared__ bf16_t Ks[128*64];    // [kv][hd], chunk-swizzled
  __shared__ bf16_t Vs[64*128];    // [hd][kv], chunk-swizzled
  __shared__ bf16_t Ps[128*128];   // [q][kv],  chunk-swizzled

  const int qt = blockIdx.x, h = blockIdx.y, b = blockIdx.z;
  const int tid = threadIdx.x, lane = tid & 63, wid = tid >> 6;
  const int q0 = qt * 128;
  const int g = lane >> 4, c = lane & 15;

  // hoist Q fragments (wave owns q rows [wid*32, wid*32+32))
  bf16x8 qf[2][2];
  #pragma unroll
  for (int m = 0; m < 2; ++m)
    #pragma unroll
    for (int kk = 0; kk < 2; ++kk) {
      size_t row = (size_t)(b*1024 + q0 + wid*32 + m*16 + c);
      qf[m][kk] = *(const bf16x8*)&Qm[row*1024 + h*64 + kk*32 + g*8];
    }

  f32x4 oacc[2][4] = {};
  float mrun[2][4], lrun[2][4];
  #pragma unroll
  for (int m = 0; m < 2; ++m)
    #pragma unroll
    for (int r = 0; r < 4; ++r) { mrun[m][r] = -1e30f; lrun[m][r] = 0.f; }

  const int sKrow = wid*32 + (lane >> 3), sKch = lane & 7;
  const int sVrow = wid*16 + (lane >> 4), sVch = lane & 15;

  for (int kt = 0; kt < 8; ++kt) {
    int kv0 = kt * 128;
    #pragma unroll
    for (int i = 0; i < 4; ++i) {      // stage K tile: 128 x 64
      int r  = sKrow + i*8;
      int ch = sKch ^ (r & 7);
      load_lds16(Km + (size_t)(b*1024 + kv0 + r)*1024 + h*64 + ch*8,
                 &Ks[(wid*32 + i*8)*64]);
    }
    #pragma unroll
    for (int i = 0; i < 4; ++i) {      // stage Vt tile: 64 x 128
      int r  = sVrow + i*4;
      int ch = sVch ^ (r & 7);
      load_lds16(Vt + (size_t)((b*16 + h)*64 + r)*1024 + kv0 + ch*8,
                 &Vs[(wid*16 + i*4)*128]);
    }
    __syncthreads();

    // S = Q K^T  (per wave: 2 m-frags x 8 n-frags)
    f32x4 s[2][8] = {};
    #pragma unroll
    for (int n = 0; n < 8; ++n) {
      #pragma unroll
      for (int kk = 0; kk < 2; ++kk) {
        int row = n*16 + c;
        int ch  = (kk*4 + g) ^ (row & 7);
        bf16x8 kf = *(const bf16x8*)&Ks[row*64 + ch*8];
        s[0][n] = __builtin_amdgcn_mfma_f32_16x16x32_bf16(qf[0][kk], kf, s[0][n], 0, 0, 0);
        s[1][n] = __builtin_amdgcn_mfma_f32_16x16x32_bf16(qf[1][kk], kf, s[1][n], 0, 0, 0);
      }
    }
    // additive key-padding bias
    #pragma unroll
    for (int n = 0; n < 8; ++n) {
      float bia = (1.0f - mask[b*1024 + kv0 + n*16 + c]) * NEG_BIG;
      #pragma unroll
      for (int m = 0; m < 2; ++m)
        #pragma unroll
        for (int r = 0; r < 4; ++r) s[m][n][r] += bia;
    }
    // online softmax (rows: m*16 + g*4 + r; reduce over lane bits 0-3 = cols)
    #pragma unroll
    for (int m = 0; m < 2; ++m) {
      float pm[4];
      #pragma unroll
      for (int r = 0; r < 4; ++r) {
        float v = s[m][0][r];
        #pragma unroll
        for (int n = 1; n < 8; ++n) v = fmaxf(v, s[m][n][r]);
        #pragma unroll
        for (int msk = 1; msk < 16; msk <<= 1)
          v = fmaxf(v, __shfl_xor(v, msk, 64));
        pm[r] = v;
      }
      #pragma unroll
      for (int r = 0; r < 4; ++r) {
        float mnew = fmaxf(mrun[m][r], pm[r]);
        float sc = __expf(mrun[m][r] - mnew);
        mrun[m][r] = mnew;
        lrun[m][r] *= sc;
        #pragma unroll
        for (int nO = 0; nO < 4; ++nO) oacc[m][nO][r] *= sc;
      }
      #pragma unroll
      for (int r = 0; r < 4; ++r) {
        float rs = 0.f;
        #pragma unroll
        for (int n = 0; n < 8; ++n) {
          float p = __expf(s[m][n][r] - mrun[m][r]);
          s[m][n][r] = p;
          rs += p;
        }
        #pragma unroll
        for (int msk = 1; msk < 16; msk <<= 1)
          rs += __shfl_xor(rs, msk, 64);
        lrun[m][r] += rs;
      }
      // P -> LDS (bf16, swizzled); own-wave rows only
      #pragma unroll
      for (int n = 0; n < 8; ++n) {
        #pragma unroll
        for (int r = 0; r < 4; ++r) {
          int row = wid*32 + m*16 + g*4 + r;
          int col = n*16 + c;
          int ch  = (col >> 3) ^ (row & 7);
          Ps[row*128 + ch*8 + (col & 7)] = (bf16_t)s[m][n][r];
        }
      }
    }
    // PV (P rows are own-wave: ds dependency handled by lgkmcnt, no barrier needed)
    #pragma unroll
    for (int ks = 0; ks < 4; ++ks) {
      bf16x8 pf[2], vf[4];
      #pragma unroll
      for (int m = 0; m < 2; ++m) {
        int row = wid*32 + m*16 + c;
        int ch  = (ks*4 + g) ^ (row & 7);
        pf[m] = *(const bf16x8*)&Ps[row*128 + ch*8];
      }
      #pragma unroll
      for (int nO = 0; nO < 4; ++nO) {
        int row = nO*16 + c;
        int ch  = (ks*4 + g) ^ (row & 7);
        vf[nO] = *(const bf16x8*)&Vs[row*128 + ch*8];
      }
      #pragma unroll
      for (int m = 0; m < 2; ++m)
        #pragma unroll
        for (int nO = 0; nO < 4; ++nO)
          oacc[m][nO] = __builtin_amdgcn_mfma_f32_16x16x32_bf16(pf[m], vf[nO], oacc[m][nO], 0, 0, 0);
    }
    __syncthreads();
  }

  // normalize + write X2 (bf16, layout [b*S+q][h*64+hd])
  #pragma unroll
  for (int m = 0; m < 2; ++m) {
    float inv[4];
    #pragma unroll
    for (int r = 0; r < 4; ++r) inv[r] = 1.0f / lrun[m][r];
    #pragma unroll
    for (int nO = 0; nO < 4; ++nO) {
      int col = h*64 + nO*16 + c;
      #pragma unroll
      for (int r = 0; r < 4; ++r) {
        size_t row = (size_t)(b*1024 + q0 + wid*32 + m*16 + g*4 + r);
        X2[row*1024 + col] = (bf16_t)(oacc[m][nO][r] * inv[r]);
      }
    }
  }
}

// ---------------- 6) output GEMM: out = X2 * Wot^T + bo (fp32 out) ----------------
__global__ __launch_bounds__(256, 2) void k_gemm_out(
    const bf16_t* __restrict__ A, const bf16_t* __restrict__ Bt,
    const float* __restrict__ bo, float* __restrict__ C)
{
  __shared__ bf16_t As[128*64];
  __shared__ bf16_t Bs[128*64];

  const int tid = threadIdx.x, lane = tid & 63, wid = tid >> 6;
  const int wm = wid >> 1, wn = wid & 1;
  const int bm0 = blockIdx.y * 128, bn0 = blockIdx.x * 128;
  const int g = lane >> 4, c = lane & 15;

  f32x4 acc[4][4] = {};
  const int srow = wid*32 + (lane >> 3);
  const int sch  = lane & 7;

  for (int kt = 0; kt < 16; ++kt) {
    int k0 = kt * 64;
    #pragma unroll
    for (int i = 0; i < 4; ++i) {
      int r  = srow + i*8;
      int ca = sch ^ (r & 7);
      load_lds16(A  + (size_t)(bm0 + r)*1024 + k0 + ca*8, &As[(wid*32 + i*8)*64]);
      load_lds16(Bt + (size_t)(bn0 + r)*1024 + k0 + ca*8, &Bs[(wid*32 + i*8)*64]);
    }
    __syncthreads();
    #pragma unroll
    for (int kk = 0; kk < 2; ++kk) {
      bf16x8 af[4], bfr[4];
      #pragma unroll
      for (int m = 0; m < 4; ++m) {
        int row = wm*64 + m*16 + c;
        int ch  = (kk*4 + g) ^ (row & 7);
        af[m] = *(const bf16x8*)&As[row*64 + ch*8];
      }
      #pragma unroll
      for (int n = 0; n < 4; ++n) {
        int row = wn*64 + n*16 + c;
        int ch  = (kk*4 + g) ^ (row & 7);
        bfr[n] = *(const bf16x8*)&Bs[row*64 + ch*8];
      }
      #pragma unroll
      for (int m = 0; m < 4; ++m)
        #pragma unroll
        for (int n = 0; n < 4; ++n)
          acc[m][n] = __builtin_amdgcn_mfma_f32_16x16x32_bf16(af[m], bfr[n], acc[m][n], 0, 0, 0);
    }
    __syncthreads();
  }

  #pragma unroll
  for (int n = 0; n < 4; ++n) {
    int col = bn0 + wn*64 + n*16 + c;
    float bn_ = bo[col];
    #pragma unroll
    for (int m = 0; m < 4; ++m) {
      int row0 = bm0 + wm*64 + m*16 + g*4;
      #pragma unroll
      for (int r = 0; r < 4; ++r)
        C[(size_t)(row0 + r)*1024 + col] = acc[m][n][r] + bn_;
    }
  }
}

extern "C" void kernel_launch(void* const* d_in, const int* in_sizes, int n_in,
                              void* d_out, int out_size, void* d_ws, size_t ws_size,
                              hipStream_t stream) {
  const float* iq   = (const float*)d_in[0];
  const float* ikv  = (const float*)d_in[1];
  const float* pq   = (const float*)d_in[2];
  const float* pk   = (const float*)d_in[3];
  const float* pv   = (const float*)d_in[4];
  const float* mask = (const float*)d_in[5];
  const float* wq   = (const float*)d_in[6];
  const float* bq   = (const float*)d_in[7];
  const float* wk   = (const float*)d_in[8];
  const float* bk   = (const float*)d_in[9];
  const float* wv   = (const float*)d_in[10];
  const float* bv   = (const float*)d_in[11];
  const float* wo   = (const float*)d_in[12];
  const float* bo   = (const float*)d_in[13];
  float* out = (float*)d_out;

  char* ws = (char*)d_ws;
  bf16_t* Xq  = (bf16_t*)(ws + (size_t)( 0u<<20));
  bf16_t* Xk  = (bf16_t*)(ws + (size_t)( 8u<<20));
  bf16_t* Xv  = (bf16_t*)(ws + (size_t)(16u<<20));
  bf16_t* Wqt = (bf16_t*)(ws + (size_t)(24u<<20));
  bf16_t* Wkt = (bf16_t*)(ws + (size_t)(26u<<20));
  bf16_t* Wvt = (bf16_t*)(ws + (size_t)(28u<<20));
  bf16_t* Wot = (bf16_t*)(ws + (size_t)(30u<<20));
  bf16_t* Q   = (bf16_t*)(ws + (size_t)(32u<<20));
  bf16_t* K   = (bf16_t*)(ws + (size_t)(40u<<20));
  bf16_t* V   = (bf16_t*)(ws + (size_t)(48u<<20));
  bf16_t* Vt  = (bf16_t*)(ws + (size_t)(56u<<20));
  bf16_t* X2  = (bf16_t*)(ws + (size_t)(64u<<20));

  k_prep<<<4096, 256, 0, stream>>>((const float4*)iq, (const float4*)ikv,
      (const float4*)pq, (const float4*)pk, (const float4*)pv, Xq, Xk, Xv);
  k_wtrans<<<dim3(16,16,4), 256, 0, stream>>>(wq, wk, wv, wo, Wqt, Wkt, Wvt, Wot);
  k_gemm_qkv<<<dim3(8,32,3), 256, 0, stream>>>(Xq, Xk, Xv, Wqt, Wkt, Wvt,
                                               bq, bk, bv, Q, K, V);
  k_vtrans<<<dim3(16,64), 256, 0, stream>>>(V, Vt);
  k_attn<<<dim3(8,16,4), 256, 0, stream>>>(Q, K, Vt, mask, X2);
  k_gemm_out<<<dim3(8,32), 256, 0, stream>>>(X2, Wot, bo, out);
}

// Round 2
// 122.037 us; speedup vs baseline: 1.1269x; 1.1269x over previous
//
#include <hip/hip_runtime.h>
#include <hip/hip_bf16.h>
#include <stdint.h>

typedef __bf16 bf16_t;
typedef __bf16 bf16x8 __attribute__((ext_vector_type(8)));
typedef __bf16 bf16x4v __attribute__((ext_vector_type(4)));
typedef float  f32x4  __attribute__((ext_vector_type(4)));
typedef float  f32x16 __attribute__((ext_vector_type(16)));
typedef unsigned int u32;
typedef u32 u32x4 __attribute__((ext_vector_type(4)));

#define NEG_BIG (-1e10f)

// async global->LDS, 16B per lane; LDS dest = wave-uniform base + lane*16
__device__ __forceinline__ void load_lds16(const void* gsrc, void* ldst) {
  __builtin_amdgcn_global_load_lds(
      (__attribute__((address_space(1))) void*)(gsrc),
      (__attribute__((address_space(3))) void*)(ldst), 16, 0, 0);
}

__device__ __forceinline__ u32 cvt_pk_bf16(float lo, float hi) {
  u32 r;
  asm("v_cvt_pk_bf16_f32 %0, %1, %2" : "=v"(r) : "v"(lo), "v"(hi));
  return r;
}

// ---------------- 1) fused add + bf16 cast ----------------
__global__ __launch_bounds__(256) void k_prep(
    const float4* __restrict__ iq, const float4* __restrict__ ikv,
    const float4* __restrict__ pq, const float4* __restrict__ pk,
    const float4* __restrict__ pv,
    bf16_t* __restrict__ Xq, bf16_t* __restrict__ Xk, bf16_t* __restrict__ Xv)
{
  int i = blockIdx.x * 256 + threadIdx.x;   // 0 .. 4096*1024/4
  float4 a = iq[i], b = ikv[i];
  float4 eq = pq[i], ek = pk[i], ev = pv[i];
  bf16x4v q, k, v;
  q[0] = (bf16_t)(a.x + eq.x); q[1] = (bf16_t)(a.y + eq.y);
  q[2] = (bf16_t)(a.z + eq.z); q[3] = (bf16_t)(a.w + eq.w);
  k[0] = (bf16_t)(b.x + ek.x); k[1] = (bf16_t)(b.y + ek.y);
  k[2] = (bf16_t)(b.z + ek.z); k[3] = (bf16_t)(b.w + ek.w);
  v[0] = (bf16_t)(b.x + ev.x); v[1] = (bf16_t)(b.y + ev.y);
  v[2] = (bf16_t)(b.z + ev.z); v[3] = (bf16_t)(b.w + ev.w);
  *(bf16x4v*)&Xq[(size_t)i*4] = q;
  *(bf16x4v*)&Xk[(size_t)i*4] = k;
  *(bf16x4v*)&Xv[(size_t)i*4] = v;
}

// ---------------- 2) weight transpose + cast: W[k][n] -> Wt[n][k] bf16 ----------------
__global__ __launch_bounds__(256) void k_wtrans(
    const float* __restrict__ wq, const float* __restrict__ wk,
    const float* __restrict__ wv, const float* __restrict__ wo,
    bf16_t* __restrict__ Wqt, bf16_t* __restrict__ Wkt,
    bf16_t* __restrict__ Wvt, bf16_t* __restrict__ Wot)
{
  __shared__ float t[64][65];
  int z = blockIdx.z;
  const float* src = z==0 ? wq : z==1 ? wk : z==2 ? wv : wo;
  bf16_t*      dst = z==0 ? Wqt : z==1 ? Wkt : z==2 ? Wvt : Wot;
  int n0 = blockIdx.x * 64, k0 = blockIdx.y * 64;
  int c = threadIdx.x & 63, rb = threadIdx.x >> 6;
  #pragma unroll
  for (int i = 0; i < 16; ++i) {
    int r = i*4 + rb;
    t[r][c] = src[(size_t)(k0 + r)*1024 + n0 + c];
  }
  __syncthreads();
  #pragma unroll
  for (int i = 0; i < 16; ++i) {
    int r = i*4 + rb;
    dst[(size_t)(n0 + r)*1024 + k0 + c] = (bf16_t)t[c][r];
  }
}

// ---------------- 3) QKV GEMM: C = A(M x 1024) * Bt(N x 1024)^T, 128x128 tile, BK=64 ----------------
__global__ __launch_bounds__(256, 2) void k_gemm_qkv(
    const bf16_t* __restrict__ Xq, const bf16_t* __restrict__ Xk, const bf16_t* __restrict__ Xv,
    const bf16_t* __restrict__ Wqt, const bf16_t* __restrict__ Wkt, const bf16_t* __restrict__ Wvt,
    const float* __restrict__ bq, const float* __restrict__ bk, const float* __restrict__ bv,
    bf16_t* __restrict__ Qo, bf16_t* __restrict__ Ko, bf16_t* __restrict__ Vo)
{
  int z = blockIdx.z;
  const bf16_t* A  = z==0 ? Xq : z==1 ? Xk : Xv;
  const bf16_t* Bt = z==0 ? Wqt : z==1 ? Wkt : Wvt;
  const float* bias = z==0 ? bq : z==1 ? bk : bv;
  bf16_t* C = z==0 ? Qo : z==1 ? Ko : Vo;
  const float scale = (z==0) ? 0.125f : 1.0f;

  __shared__ bf16_t As[128*64];
  __shared__ bf16_t Bs[128*64];

  const int tid = threadIdx.x, lane = tid & 63, wid = tid >> 6;
  const int wm = wid >> 1, wn = wid & 1;
  const int bm0 = blockIdx.y * 128, bn0 = blockIdx.x * 128;
  const int g = lane >> 4, c = lane & 15;

  f32x4 acc[4][4] = {};

  const int srow = wid*32 + (lane >> 3);  // + i*8
  const int sch  = lane & 7;

  for (int kt = 0; kt < 16; ++kt) {
    int k0 = kt * 64;
    #pragma unroll
    for (int i = 0; i < 4; ++i) {
      int r  = srow + i*8;
      int ca = sch ^ (r & 7);             // source pre-swizzle (chunk XOR row&7)
      load_lds16(A  + (size_t)(bm0 + r)*1024 + k0 + ca*8, &As[(wid*32 + i*8)*64]);
      load_lds16(Bt + (size_t)(bn0 + r)*1024 + k0 + ca*8, &Bs[(wid*32 + i*8)*64]);
    }
    __syncthreads();
    #pragma unroll
    for (int kk = 0; kk < 2; ++kk) {
      bf16x8 af[4], bfr[4];
      #pragma unroll
      for (int m = 0; m < 4; ++m) {
        int row = wm*64 + m*16 + c;
        int ch  = (kk*4 + g) ^ (row & 7);
        af[m] = *(const bf16x8*)&As[row*64 + ch*8];
      }
      #pragma unroll
      for (int n = 0; n < 4; ++n) {
        int row = wn*64 + n*16 + c;
        int ch  = (kk*4 + g) ^ (row & 7);
        bfr[n] = *(const bf16x8*)&Bs[row*64 + ch*8];
      }
      #pragma unroll
      for (int m = 0; m < 4; ++m)
        #pragma unroll
        for (int n = 0; n < 4; ++n)
          acc[m][n] = __builtin_amdgcn_mfma_f32_16x16x32_bf16(af[m], bfr[n], acc[m][n], 0, 0, 0);
    }
    __syncthreads();
  }

  #pragma unroll
  for (int n = 0; n < 4; ++n) {
    int col = bn0 + wn*64 + n*16 + c;
    float bn_ = bias[col];
    #pragma unroll
    for (int m = 0; m < 4; ++m) {
      int row0 = bm0 + wm*64 + m*16 + g*4;
      #pragma unroll
      for (int r = 0; r < 4; ++r) {
        float v = (acc[m][n][r] + bn_) * scale;
        C[(size_t)(row0 + r)*1024 + col] = (bf16_t)v;
      }
    }
  }
}

// ---------------- 4) V transpose: per (b,h) [s][hd] -> Vt[hd][s] ----------------
__global__ __launch_bounds__(256) void k_vtrans(
    const bf16_t* __restrict__ V, bf16_t* __restrict__ Vt)
{
  __shared__ uint32_t t[64][65];
  int bh = blockIdx.y;              // b*16+h
  int s0 = blockIdx.x * 64;
  int b = bh >> 4, h = bh & 15;
  int c = threadIdx.x & 63, rb = threadIdx.x >> 6;
  const uint16_t* src = (const uint16_t*)V + (size_t)(b*1024 + s0)*1024 + h*64;
  #pragma unroll
  for (int i = 0; i < 16; ++i) {
    int r = i*4 + rb;              // s within tile
    t[r][c] = src[(size_t)r*1024 + c];
  }
  __syncthreads();
  uint16_t* dst = (uint16_t*)Vt + (size_t)(bh*64)*1024 + s0;
  #pragma unroll
  for (int i = 0; i < 16; ++i) {
    int r = i*4 + rb;              // hd
    dst[(size_t)r*1024 + c] = (uint16_t)t[c][r];
  }
}

// ---------------- 5) flash attention, swapped-QK^T (S^T = K·Q), 32x32x16 MFMA ----------------
// Per block: 4 waves x QBLK=32 rows = 128 q; KVBLK=64, double-buffered K / Vt LDS.
// Lane state after QK^T: s[blk][r] = S[kv = blk*32 + (r&3)+8*(r>>2)+4*hi][q = lane&31].
__global__ __launch_bounds__(256, 2) void k_attn2(
    const bf16_t* __restrict__ Qm, const bf16_t* __restrict__ Km,
    const bf16_t* __restrict__ Vt, const float* __restrict__ mask,
    bf16_t* __restrict__ X2)
{
  __shared__ bf16_t Ks[2][64*64];     // [kv][hd], chunk-swizzled
  __shared__ bf16_t Vs[2][64*64];     // [hd][kv], chunk-swizzled
  __shared__ float  bias_lds[1024];   // (1-mask)*NEG_BIG for this batch
  __shared__ float  l_lds[4][32];

  const int qt = blockIdx.x, h = blockIdx.y, b = blockIdx.z;
  const int tid = threadIdx.x, lane = tid & 63, wid = tid >> 6;
  const int lq = lane & 31;           // q column (C col = B row)
  const int hi = lane >> 5;

  // stage additive bias for the whole row of this batch (4 KB)
  {
    float4 m4 = *(const float4*)&mask[b*1024 + tid*4];
    float4 b4;
    b4.x = (1.0f - m4.x) * NEG_BIG;
    b4.y = (1.0f - m4.y) * NEG_BIG;
    b4.z = (1.0f - m4.z) * NEG_BIG;
    b4.w = (1.0f - m4.w) * NEG_BIG;
    *(float4*)&bias_lds[tid*4] = b4;
  }

  // hoist Q B-fragments: lane holds Q[q0w+lq][kb*16 + hi*8 + j]  (Q pre-scaled by 1/8)
  const int q0w = qt*128 + wid*32;
  bf16x8 qf[4];
  #pragma unroll
  for (int kb = 0; kb < 4; ++kb)
    qf[kb] = *(const bf16x8*)&Qm[(size_t)(b*1024 + q0w + lq)*1024 + h*64 + kb*16 + hi*8];

  f32x16 oacc[2] = {};
  float mrow = -1e30f, lsum = 0.f;

  // staging: tile 64 rows x 64 bf16 (128B rows); per wave 2 calls of 8 rows
  const int sr8 = (lane >> 3);        // row-in-8
  const int sc8 = lane & 7;           // 16B chunk
  #define STAGE(bufi, kv0)                                                        \
    {                                                                             \
      _Pragma("unroll")                                                           \
      for (int cc = 0; cc < 2; ++cc) {                                            \
        int r  = cc*32 + wid*8 + sr8;                                             \
        int ca = sc8 ^ (r & 7);                                                   \
        load_lds16(Km + (size_t)(b*1024 + (kv0) + r)*1024 + h*64 + ca*8,          \
                   &Ks[bufi][(cc*32 + wid*8)*64]);                                \
        load_lds16(Vt + (size_t)((b*16 + h)*64 + r)*1024 + (kv0) + ca*8,          \
                   &Vs[bufi][(cc*32 + wid*8)*64]);                                \
      }                                                                           \
    }

  STAGE(0, 0);
  __syncthreads();                     // covers bias_lds too

  for (int kt = 0; kt < 16; ++kt) {
    const int buf = kt & 1;
    if (kt < 15) STAGE(buf ^ 1, (kt + 1) * 64);

    // ---- S^T = K * Q  (A = K rows, B = Q rows) ----
    f32x16 s[2];
    #pragma unroll
    for (int blk = 0; blk < 2; ++blk) {
      f32x16 acc = {};
      #pragma unroll
      for (int kb = 0; kb < 4; ++kb) {
        int row = blk*32 + lq;
        int ch  = (kb*2 + hi) ^ (row & 7);
        bf16x8 kf = *(const bf16x8*)&Ks[buf][row*64 + ch*8];
        acc = __builtin_amdgcn_mfma_f32_32x32x16_bf16(kf, qf[kb], acc, 0, 0, 0);
      }
      s[blk] = acc;
    }

    // ---- additive key-padding bias (kv = kt*64 + blk*32 + j + 8*g2 + 4*hi) ----
    #pragma unroll
    for (int blk = 0; blk < 2; ++blk)
      #pragma unroll
      for (int g2 = 0; g2 < 4; ++g2) {
        float4 b4 = *(const float4*)&bias_lds[kt*64 + blk*32 + g2*8 + hi*4];
        s[blk][g2*4+0] += b4.x;
        s[blk][g2*4+1] += b4.y;
        s[blk][g2*4+2] += b4.z;
        s[blk][g2*4+3] += b4.w;
      }

    // ---- online softmax: lane-local over 32 kv + cross-hi shuffle ----
    float pmax = s[0][0];
    #pragma unroll
    for (int blk = 0; blk < 2; ++blk)
      #pragma unroll
      for (int r = 0; r < 16; ++r) pmax = fmaxf(pmax, s[blk][r]);
    pmax = fmaxf(pmax, __shfl_xor(pmax, 32, 64));

    if (!__all(pmax - mrow <= 8.0f)) {        // defer-max (T13)
      float mnew = fmaxf(mrow, pmax);
      float sc = __expf(mrow - mnew);
      lsum *= sc;
      #pragma unroll
      for (int nb = 0; nb < 2; ++nb)
        #pragma unroll
        for (int i = 0; i < 16; ++i) oacc[nb][i] *= sc;
      mrow = mnew;
    }

    float rs = 0.f;
    #pragma unroll
    for (int blk = 0; blk < 2; ++blk)
      #pragma unroll
      for (int r = 0; r < 16; ++r) {
        float p = __expf(s[blk][r] - mrow);
        s[blk][r] = p;
        rs += p;
      }
    lsum += rs + __shfl_xor(rs, 32, 64);

    // ---- P -> bf16 A-fragments in-register (T12: cvt_pk + permlane32_swap) ----
    u32 paw[4][4];
    #pragma unroll
    for (int blk = 0; blk < 2; ++blk)
      #pragma unroll
      for (int half = 0; half < 2; ++half) {   // k-slot ks = blk*2 + half
        int base = half * 8;
        #pragma unroll
        for (int w = 0; w < 2; ++w) {
          u32 x = cvt_pk_bf16(s[blk][base + 2*w],     s[blk][base + 2*w + 1]);
          u32 y = cvt_pk_bf16(s[blk][base + 4 + 2*w], s[blk][base + 4 + 2*w + 1]);
          asm("v_permlane32_swap_b32 %0, %1" : "+v"(x), "+v"(y));
          paw[blk*2 + half][w]     = x;        // k = hi*8 + {2w, 2w+1}
          paw[blk*2 + half][w + 2] = y;        // k = hi*8 + {2w+4, 2w+5}
        }
      }

    // ---- PV: O[q][hd] += P * V ----
    #pragma unroll
    for (int ks = 0; ks < 4; ++ks) {
      u32x4 t = { paw[ks][0], paw[ks][1], paw[ks][2], paw[ks][3] };
      bf16x8 pa = __builtin_bit_cast(bf16x8, t);
      #pragma unroll
      for (int nb = 0; nb < 2; ++nb) {
        int row = nb*32 + lq;
        int ch  = (ks*2 + hi) ^ (row & 7);
        bf16x8 vf = *(const bf16x8*)&Vs[buf][row*64 + ch*8];
        oacc[nb] = __builtin_amdgcn_mfma_f32_32x32x16_bf16(pa, vf, oacc[nb], 0, 0, 0);
      }
    }
    __syncthreads();
  }

  // ---- epilogue: redistribute l (per-q) and write X2 ----
  l_lds[wid][lq] = lsum;
  __syncthreads();
  #pragma unroll
  for (int g2 = 0; g2 < 4; ++g2)
    #pragma unroll
    for (int j = 0; j < 4; ++j) {
      int reg  = g2*4 + j;
      int qrow = j + 8*g2 + 4*hi;
      float inv = 1.0f / l_lds[wid][qrow];
      #pragma unroll
      for (int nb = 0; nb < 2; ++nb)
        X2[(size_t)(b*1024 + q0w + qrow)*1024 + h*64 + nb*32 + lq] =
            (bf16_t)(oacc[nb][reg] * inv);
    }
  #undef STAGE
}

// ---------------- 6) output GEMM: out = X2 * Wot^T + bo (fp32 out) ----------------
__global__ __launch_bounds__(256, 2) void k_gemm_out(
    const bf16_t* __restrict__ A, const bf16_t* __restrict__ Bt,
    const float* __restrict__ bo, float* __restrict__ C)
{
  __shared__ bf16_t As[128*64];
  __shared__ bf16_t Bs[128*64];

  const int tid = threadIdx.x, lane = tid & 63, wid = tid >> 6;
  const int wm = wid >> 1, wn = wid & 1;
  const int bm0 = blockIdx.y * 128, bn0 = blockIdx.x * 128;
  const int g = lane >> 4, c = lane & 15;

  f32x4 acc[4][4] = {};
  const int srow = wid*32 + (lane >> 3);
  const int sch  = lane & 7;

  for (int kt = 0; kt < 16; ++kt) {
    int k0 = kt * 64;
    #pragma unroll
    for (int i = 0; i < 4; ++i) {
      int r  = srow + i*8;
      int ca = sch ^ (r & 7);
      load_lds16(A  + (size_t)(bm0 + r)*1024 + k0 + ca*8, &As[(wid*32 + i*8)*64]);
      load_lds16(Bt + (size_t)(bn0 + r)*1024 + k0 + ca*8, &Bs[(wid*32 + i*8)*64]);
    }
    __syncthreads();
    #pragma unroll
    for (int kk = 0; kk < 2; ++kk) {
      bf16x8 af[4], bfr[4];
      #pragma unroll
      for (int m = 0; m < 4; ++m) {
        int row = wm*64 + m*16 + c;
        int ch  = (kk*4 + g) ^ (row & 7);
        af[m] = *(const bf16x8*)&As[row*64 + ch*8];
      }
      #pragma unroll
      for (int n = 0; n < 4; ++n) {
        int row = wn*64 + n*16 + c;
        int ch  = (kk*4 + g) ^ (row & 7);
        bfr[n] = *(const bf16x8*)&Bs[row*64 + ch*8];
      }
      #pragma unroll
      for (int m = 0; m < 4; ++m)
        #pragma unroll
        for (int n = 0; n < 4; ++n)
          acc[m][n] = __builtin_amdgcn_mfma_f32_16x16x32_bf16(af[m], bfr[n], acc[m][n], 0, 0, 0);
    }
    __syncthreads();
  }

  #pragma unroll
  for (int n = 0; n < 4; ++n) {
    int col = bn0 + wn*64 + n*16 + c;
    float bn_ = bo[col];
    #pragma unroll
    for (int m = 0; m < 4; ++m) {
      int row0 = bm0 + wm*64 + m*16 + g*4;
      #pragma unroll
      for (int r = 0; r < 4; ++r)
        C[(size_t)(row0 + r)*1024 + col] = acc[m][n][r] + bn_;
    }
  }
}

extern "C" void kernel_launch(void* const* d_in, const int* in_sizes, int n_in,
                              void* d_out, int out_size, void* d_ws, size_t ws_size,
                              hipStream_t stream) {
  const float* iq   = (const float*)d_in[0];
  const float* ikv  = (const float*)d_in[1];
  const float* pq   = (const float*)d_in[2];
  const float* pk   = (const float*)d_in[3];
  const float* pv   = (const float*)d_in[4];
  const float* mask = (const float*)d_in[5];
  const float* wq   = (const float*)d_in[6];
  const float* bq   = (const float*)d_in[7];
  const float* wk   = (const float*)d_in[8];
  const float* bk   = (const float*)d_in[9];
  const float* wv   = (const float*)d_in[10];
  const float* bv   = (const float*)d_in[11];
  const float* wo   = (const float*)d_in[12];
  const float* bo   = (const float*)d_in[13];
  float* out = (float*)d_out;

  char* ws = (char*)d_ws;
  bf16_t* Xq  = (bf16_t*)(ws + (size_t)( 0u<<20));
  bf16_t* Xk  = (bf16_t*)(ws + (size_t)( 8u<<20));
  bf16_t* Xv  = (bf16_t*)(ws + (size_t)(16u<<20));
  bf16_t* Wqt = (bf16_t*)(ws + (size_t)(24u<<20));
  bf16_t* Wkt = (bf16_t*)(ws + (size_t)(26u<<20));
  bf16_t* Wvt = (bf16_t*)(ws + (size_t)(28u<<20));
  bf16_t* Wot = (bf16_t*)(ws + (size_t)(30u<<20));
  bf16_t* Q   = (bf16_t*)(ws + (size_t)(32u<<20));
  bf16_t* K   = (bf16_t*)(ws + (size_t)(40u<<20));
  bf16_t* V   = (bf16_t*)(ws + (size_t)(48u<<20));
  bf16_t* Vt  = (bf16_t*)(ws + (size_t)(56u<<20));
  bf16_t* X2  = (bf16_t*)(ws + (size_t)(64u<<20));

  k_prep<<<4096, 256, 0, stream>>>((const float4*)iq, (const float4*)ikv,
      (const float4*)pq, (const float4*)pk, (const float4*)pv, Xq, Xk, Xv);
  k_wtrans<<<dim3(16,16,4), 256, 0, stream>>>(wq, wk, wv, wo, Wqt, Wkt, Wvt, Wot);
  k_gemm_qkv<<<dim3(8,32,3), 256, 0, stream>>>(Xq, Xk, Xv, Wqt, Wkt, Wvt,
                                               bq, bk, bv, Q, K, V);
  k_vtrans<<<dim3(16,64), 256, 0, stream>>>(V, Vt);
  k_attn2<<<dim3(8,16,4), 256, 0, stream>>>(Q, K, Vt, mask, X2);
  k_gemm_out<<<dim3(8,32), 256, 0, stream>>>(X2, Wot, bo, out);
}